// Round 4
// baseline (175.920 us; speedup 1.0000x reference)
//
#include <hip/hip_runtime.h>

// Problem constants (reference: B=2, N=2048, DIM=512, H=8, DH=64)
constexpr int kB   = 2;
constexpr int kN   = 2048;
constexpr int kDIM = 512;
constexpr int kH   = 8;
constexpr int kDH  = 64;
constexpr int kBH  = kB * kH;          // 16
constexpr int NROWS = kB * kN;         // 4096
constexpr int CHUNK = 64;
constexpr int NCH   = kN / CHUNK;      // 32
constexpr int CBSTRIDE = kDH * kDH + kDH;  // 4160 per (bh,chunk): ST[e][d] (4096) + z (64)
constexpr float kEPS = 1e-3f;

typedef _Float16 f16x8 __attribute__((ext_vector_type(8)));
typedef _Float16 f16x4 __attribute__((ext_vector_type(4)));
typedef float    floatx4 __attribute__((ext_vector_type(4)));

__device__ __forceinline__ void async_copy16(void* lds, const void* g) {
    __builtin_amdgcn_global_load_lds(
        (const __attribute__((address_space(1))) void*)g,
        (__attribute__((address_space(3))) void*)lds,
        16, 0, 0);
}

// Grid-wide barrier: all `nb` blocks must be co-resident (they are: 512 blocks,
// ~9KB LDS, 4 waves/block << CU capacity).  Counter is monotonic per launch,
// zeroed by prep_kernel each call.
__device__ __forceinline__ void grid_barrier(unsigned* cnt, unsigned target) {
    __syncthreads();
    if (threadIdx.x == 0) {
        __threadfence();   // release: make this block's writes visible (agent)
        __hip_atomic_fetch_add(cnt, 1u, __ATOMIC_ACQ_REL, __HIP_MEMORY_SCOPE_AGENT);
        while (__hip_atomic_load(cnt, __ATOMIC_ACQUIRE, __HIP_MEMORY_SCOPE_AGENT) < target)
            __builtin_amdgcn_s_sleep(2);
        __threadfence();   // acquire: invalidate stale cached lines
    }
    __syncthreads();
}

// ---------------------------------------------------------------------------
// Prep: transpose+convert weights to fp16 (WT[n][k]); zero barrier counter.
// z = 0,1,2 -> Wq,Wk,Wv into fused WT[1536][512]; z = 3 -> Wo into WoT.
// ---------------------------------------------------------------------------
__global__ __launch_bounds__(256)
void prep_kernel(const float* __restrict__ Wq, const float* __restrict__ Wk,
                 const float* __restrict__ Wv, const float* __restrict__ Wo,
                 _Float16* __restrict__ WT, _Float16* __restrict__ WoT,
                 unsigned* __restrict__ cnt)
{
    if (blockIdx.x == 0 && blockIdx.y == 0 && blockIdx.z == 0 && threadIdx.x < 4)
        cnt[threadIdx.x] = 0u;
    __shared__ float tile[32][33];
    const int z = blockIdx.z;
    const float* src = (z == 0) ? Wq : (z == 1) ? Wk : (z == 2) ? Wv : Wo;
    _Float16* dst = (z < 3) ? (WT + (size_t)z * 512 * 512) : WoT;
    const int r0 = blockIdx.y * 32, c0 = blockIdx.x * 32;
    const int tr = threadIdx.x >> 5, tc = threadIdx.x & 31;
    #pragma unroll
    for (int i = 0; i < 4; ++i)
        tile[tr + 8 * i][tc] = src[(size_t)(r0 + tr + 8 * i) * 512 + c0 + tc];
    __syncthreads();
    #pragma unroll
    for (int i = 0; i < 4; ++i)
        dst[(size_t)(c0 + tr + 8 * i) * 512 + r0 + tc] = (_Float16)tile[tc][tr + 8 * i];
}

// ---------------------------------------------------------------------------
// MFMA GEMM.  BM=BN=128, BK=64, 256 threads (4 waves, 2x2).
// A-side: MODE 0 reads fp32 x directly (reg-staged, cvt->f16, swizzled
// ds_write_b128); MODE 1 reads fp16 attn via global_load_lds.
// B-side: fp16 *T weights via global_load_lds, XOR-swizzled source+read.
// MODE 0 epilogue -> fp16 qh,khb row-major [bh][n][64] (relu+eps on q,k),
//                    fp16 kTh,vTh transposed [bh][d][n].
// MODE 1 epilogue -> +bias, fp32 row-major [4096][512].
// ---------------------------------------------------------------------------
template<int MODE>
__global__ __launch_bounds__(256)
void mfma_gemm_kernel(const float* __restrict__ Af32,
                      const _Float16* __restrict__ Af16,
                      const _Float16* __restrict__ BT,
                      const float* __restrict__ bo,
                      float* __restrict__ outf,
                      _Float16* __restrict__ qh,
                      _Float16* __restrict__ khb,
                      _Float16* __restrict__ kTh,
                      _Float16* __restrict__ vTh)
{
    constexpr int K = 512;
    __shared__ _Float16 As[128 * 64];   // 16 KB, rows of 128 B, swizzled
    __shared__ _Float16 Bs[128 * 64];   // 16 KB

    const int t = threadIdx.x;
    const int l = t & 63;
    const int w = t >> 6;
    const int wm = w >> 1, wn = w & 1;
    const int m0 = blockIdx.y * 128;
    const int n0 = blockIdx.x * 128;

    const int r15 = l & 15, kq = l >> 4, sw = r15 & 7;

    floatx4 acc[4][4];
    #pragma unroll
    for (int mi = 0; mi < 4; ++mi)
        #pragma unroll
        for (int ni = 0; ni < 4; ++ni)
            acc[mi][ni] = (floatx4){0.f, 0.f, 0.f, 0.f};

    const int srow  = t >> 3;       // 0..31
    const int sslot = t & 7;        // 16B slot within 128B row

    const char* Bbase = (const char*)(BT + (size_t)n0 * K);
    char* AsB = (char*)As;
    char* BsB = (char*)Bs;

    const char* ArdB = (const char*)As + (wm * 64 + r15) * 128;
    const char* BrdB = (const char*)Bs + (wn * 64 + r15) * 128;
    const int sw0 = ((kq ^ sw) << 4);
    const int sw1 = (((4 + kq) ^ sw) << 4);

    for (int k0 = 0; k0 < K; k0 += 64) {
        // B tile: async global->LDS, source pre-inverse-swizzled
        #pragma unroll
        for (int i = 0; i < 4; ++i) {
            const int row = i * 32 + srow;
            const int gsl = sslot ^ (row & 7);
            async_copy16(BsB + row * 128 + sslot * 16,
                         Bbase + (size_t)row * (K * 2) + k0 * 2 + gsl * 16);
        }
        // A tile
        if (MODE == 0) {
            // reg-staged from fp32, convert, swizzled ds_write
            #pragma unroll
            for (int i = 0; i < 4; ++i) {
                const int s = i * 256 + t;          // 0..1023 16B-slots
                const int row = s >> 3, sl = s & 7;
                const float* xp = Af32 + (size_t)(m0 + row) * K + k0 + sl * 8;
                const float4 a0 = *(const float4*)(xp);
                const float4 a1 = *(const float4*)(xp + 4);
                f16x8 v;
                v[0] = (_Float16)a0.x; v[1] = (_Float16)a0.y;
                v[2] = (_Float16)a0.z; v[3] = (_Float16)a0.w;
                v[4] = (_Float16)a1.x; v[5] = (_Float16)a1.y;
                v[6] = (_Float16)a1.z; v[7] = (_Float16)a1.w;
                *(f16x8*)(AsB + row * 128 + ((sl ^ (row & 7)) << 4)) = v;
            }
        } else {
            const char* Abase = (const char*)(Af16 + (size_t)m0 * K);
            #pragma unroll
            for (int i = 0; i < 4; ++i) {
                const int row = i * 32 + srow;
                const int gsl = sslot ^ (row & 7);
                async_copy16(AsB + row * 128 + sslot * 16,
                             Abase + (size_t)row * (K * 2) + k0 * 2 + gsl * 16);
            }
        }
        __syncthreads();

        f16x8 af[4][2], bf[4][2];
        #pragma unroll
        for (int i = 0; i < 4; ++i) {
            af[i][0] = *(const f16x8*)(ArdB + i * 2048 + sw0);
            af[i][1] = *(const f16x8*)(ArdB + i * 2048 + sw1);
            bf[i][0] = *(const f16x8*)(BrdB + i * 2048 + sw0);
            bf[i][1] = *(const f16x8*)(BrdB + i * 2048 + sw1);
        }
        #pragma unroll
        for (int kk = 0; kk < 2; ++kk)
            #pragma unroll
            for (int mi = 0; mi < 4; ++mi)
                #pragma unroll
                for (int ni = 0; ni < 4; ++ni)
                    acc[mi][ni] = __builtin_amdgcn_mfma_f32_16x16x32_f16(
                        af[mi][kk], bf[ni][kk], acc[mi][ni], 0, 0, 0);
        __syncthreads();
    }

    // Epilogue.  C fragment: row = kq*4 + r, col = r15 (within each 16x16).
    if (MODE == 0) {
        #pragma unroll
        for (int ni = 0; ni < 4; ++ni) {
            const int col = n0 + wn * 64 + ni * 16 + r15;   // 0..1535
            const int which = col >> 9;
            const int h = (col >> 6) & 7, e = col & 63;
            #pragma unroll
            for (int mi = 0; mi < 4; ++mi) {
                const int row0 = m0 + wm * 64 + mi * 16 + kq * 4;
                const int b = row0 >> 11, nn = row0 & 2047;
                const int bh = b * 8 + h;
                float vv[4];
                #pragma unroll
                for (int r = 0; r < 4; ++r) {
                    float v = acc[mi][ni][r];
                    if (which < 2) v = fmaxf(v, 0.f) + kEPS;
                    vv[r] = v;
                }
                if (which == 0) {
                    #pragma unroll
                    for (int r = 0; r < 4; ++r)
                        qh[((size_t)bh * kN + nn + r) * 64 + e] = (_Float16)vv[r];
                } else if (which == 1) {
                    #pragma unroll
                    for (int r = 0; r < 4; ++r)
                        khb[((size_t)bh * kN + nn + r) * 64 + e] = (_Float16)vv[r];
                    f16x4 t4;
                    t4[0] = (_Float16)vv[0]; t4[1] = (_Float16)vv[1];
                    t4[2] = (_Float16)vv[2]; t4[3] = (_Float16)vv[3];
                    *(f16x4*)(kTh + ((size_t)bh * 64 + e) * kN + nn) = t4;
                } else {
                    f16x4 t4;
                    t4[0] = (_Float16)vv[0]; t4[1] = (_Float16)vv[1];
                    t4[2] = (_Float16)vv[2]; t4[3] = (_Float16)vv[3];
                    *(f16x4*)(vTh + ((size_t)bh * 64 + e) * kN + nn) = t4;
                }
            }
        }
    } else {
        #pragma unroll
        for (int ni = 0; ni < 4; ++ni) {
            const int col = n0 + wn * 64 + ni * 16 + r15;
            const float bias = bo[col];
            #pragma unroll
            for (int mi = 0; mi < 4; ++mi) {
                const int row = m0 + wm * 64 + mi * 16 + kq * 4;
                #pragma unroll
                for (int r = 0; r < 4; ++r)
                    outf[(size_t)(row + r) * 512 + col] = acc[mi][ni][r] + bias;
            }
        }
    }
}

// ---------------------------------------------------------------------------
// Fused mid-section: chunk sums -> grid barrier -> prefix scan -> grid barrier
// -> per-chunk output.  grid (NCH=32, BH=16) = 512 blocks, 256 threads.
// ---------------------------------------------------------------------------
__global__ __launch_bounds__(256)
void mid_kernel(const _Float16* __restrict__ qh, const _Float16* __restrict__ khb,
                const _Float16* __restrict__ kTh, const _Float16* __restrict__ vTh,
                float* __restrict__ cbuf, _Float16* __restrict__ spre16,
                float* __restrict__ zpre, _Float16* __restrict__ attnh,
                unsigned* __restrict__ cnt)
{
    const int ch = blockIdx.x, bh = blockIdx.y;
    const int t = threadIdx.x, l = t & 63, w = t >> 6;
    const int r15 = l & 15, kq = l >> 4;

    __shared__ _Float16 Plds[64 * 64];   // swizzled rows of 128 B
    __shared__ float denp[64];
    __shared__ float denf[64];

    // ---- Phase A: S_ch[e][d] = sum_n v[n][e] k[n][d];  z_ch[d] = sum_n k[n][d]
    {
        const _Float16* vbase = vTh + (size_t)bh * 64 * kN + ch * 64;
        const _Float16* kbase = kTh + (size_t)bh * 64 * kN + ch * 64;
        f16x8 av[2], bk[4][2];
        #pragma unroll
        for (int kk = 0; kk < 2; ++kk) {
            av[kk] = *(const f16x8*)(vbase + (size_t)(w * 16 + r15) * kN + kk * 32 + kq * 8);
            #pragma unroll
            for (int ni = 0; ni < 4; ++ni)
                bk[ni][kk] = *(const f16x8*)(kbase + (size_t)(ni * 16 + r15) * kN + kk * 32 + kq * 8);
        }
        floatx4 sa[4];
        #pragma unroll
        for (int ni = 0; ni < 4; ++ni) sa[ni] = (floatx4){0.f, 0.f, 0.f, 0.f};
        #pragma unroll
        for (int kk = 0; kk < 2; ++kk)
            #pragma unroll
            for (int ni = 0; ni < 4; ++ni)
                sa[ni] = __builtin_amdgcn_mfma_f32_16x16x32_f16(av[kk], bk[ni][kk], sa[ni], 0, 0, 0);

        float* outp = cbuf + ((size_t)bh * NCH + ch) * CBSTRIDE;
        #pragma unroll
        for (int ni = 0; ni < 4; ++ni)
            #pragma unroll
            for (int r = 0; r < 4; ++r)
                outp[(size_t)(w * 16 + kq * 4 + r) * 64 + ni * 16 + r15] = sa[ni][r];

        if (t < 64) {
            const _Float16* kp = kbase + (size_t)t * kN;
            float z = 0.f;
            #pragma unroll
            for (int j = 0; j < 8; ++j) {
                f16x8 v8 = *(const f16x8*)(kp + j * 8);
                #pragma unroll
                for (int u = 0; u < 8; ++u) z += (float)v8[u];
            }
            outp[4096 + t] = z;
        }
    }
    grid_barrier(cnt, NCH * kBH);

    // ---- Phase B: exclusive prefix over chunks.  Block handles 130 columns.
    {
        const int col = ch * 130 + t;      // 32*130 = 4160 exactly
        if (t < 130) {
            const float* src = cbuf + (size_t)bh * NCH * CBSTRIDE + col;
            float vals[NCH];
            #pragma unroll
            for (int c = 0; c < NCH; ++c) vals[c] = src[(size_t)c * CBSTRIDE];
            float a = 0.f;
            if (col < 4096) {
                _Float16* dst = spre16 + (size_t)bh * NCH * CBSTRIDE + col;
                #pragma unroll
                for (int c = 0; c < NCH; ++c) {
                    dst[(size_t)c * CBSTRIDE] = (_Float16)a;
                    a += vals[c];
                }
            } else {
                float* zp = zpre + (size_t)bh * NCH * 64 + (col - 4096);
                #pragma unroll
                for (int c = 0; c < NCH; ++c) {
                    zp[c * 64] = a;
                    a += vals[c];
                }
            }
        }
    }
    grid_barrier(cnt, 2 * NCH * kBH);

    // ---- Phase C: scores = QK^T (masked) -> P; O = P V + Q STpre; att = O/den
    const size_t rowbase = (size_t)bh * kN + ch * 64;

    f16x8 aq[2], bk[4][2];
    #pragma unroll
    for (int kk = 0; kk < 2; ++kk) {
        aq[kk] = *(const f16x8*)(qh + (rowbase + w * 16 + r15) * 64 + kk * 32 + kq * 8);
        #pragma unroll
        for (int ni = 0; ni < 4; ++ni)
            bk[ni][kk] = *(const f16x8*)(khb + (rowbase + ni * 16 + r15) * 64 + kk * 32 + kq * 8);
    }
    floatx4 sacc[4];
    #pragma unroll
    for (int ni = 0; ni < 4; ++ni) sacc[ni] = (floatx4){0.f, 0.f, 0.f, 0.f};
    #pragma unroll
    for (int kk = 0; kk < 2; ++kk)
        #pragma unroll
        for (int ni = 0; ni < 4; ++ni)
            sacc[ni] = __builtin_amdgcn_mfma_f32_16x16x32_f16(aq[kk], bk[ni][kk], sacc[ni], 0, 0, 0);

    const int qrow = w * 16 + kq * 4;
    float psum[4] = {0.f, 0.f, 0.f, 0.f};
    #pragma unroll
    for (int ni = 0; ni < 4; ++ni) {
        const int m = ni * 16 + r15;
        #pragma unroll
        for (int r = 0; r < 4; ++r) {
            const int row = qrow + r;
            const float v = (m <= row) ? sacc[ni][r] : 0.f;
            psum[r] += v;
            const int byte = row * 128 + ((((unsigned)m >> 3) ^ (row & 7)) << 4) + (m & 7) * 2;
            *(_Float16*)((char*)Plds + byte) = (_Float16)v;
        }
    }
    #pragma unroll
    for (int r = 0; r < 4; ++r) {
        float p = psum[r];
        p += __shfl_xor(p, 1, 16);
        p += __shfl_xor(p, 2, 16);
        p += __shfl_xor(p, 4, 16);
        p += __shfl_xor(p, 8, 16);
        if (r15 == 0) denp[qrow + r] = p;
    }
    __syncthreads();

    if (t < 64) {
        const _Float16* qp = qh + (rowbase + t) * 64;
        const float* zp = zpre + ((size_t)bh * NCH + ch) * 64;
        float s = denp[t];
        #pragma unroll
        for (int j = 0; j < 8; ++j) {
            f16x8 q8 = *(const f16x8*)(qp + j * 8);
            #pragma unroll
            for (int u = 0; u < 8; ++u) s += (float)q8[u] * zp[j * 8 + u];
        }
        denf[t] = 1.0f / s;
    }

    f16x8 ap[2], bv[4][2], bs[4][2];
    #pragma unroll
    for (int km = 0; km < 2; ++km)
        ap[km] = *(const f16x8*)((char*)Plds + (w * 16 + r15) * 128 +
                                 (((km * 4 + kq) ^ (r15 & 7)) << 4));
    #pragma unroll
    for (int ni = 0; ni < 4; ++ni) {
        #pragma unroll
        for (int km = 0; km < 2; ++km)
            bv[ni][km] = *(const f16x8*)(vTh + ((size_t)bh * 64 + ni * 16 + r15) * kN +
                                         ch * 64 + km * 32 + kq * 8);
    }
    const _Float16* sp = spre16 + ((size_t)bh * NCH + ch) * CBSTRIDE;
    #pragma unroll
    for (int ni = 0; ni < 4; ++ni)
        #pragma unroll
        for (int kd = 0; kd < 2; ++kd)
            bs[ni][kd] = *(const f16x8*)(sp + (size_t)(ni * 16 + r15) * 64 + kd * 32 + kq * 8);

    floatx4 oacc[4];
    #pragma unroll
    for (int ni = 0; ni < 4; ++ni) oacc[ni] = (floatx4){0.f, 0.f, 0.f, 0.f};
    #pragma unroll
    for (int km = 0; km < 2; ++km)
        #pragma unroll
        for (int ni = 0; ni < 4; ++ni)
            oacc[ni] = __builtin_amdgcn_mfma_f32_16x16x32_f16(ap[km], bv[ni][km], oacc[ni], 0, 0, 0);
    #pragma unroll
    for (int kd = 0; kd < 2; ++kd)
        #pragma unroll
        for (int ni = 0; ni < 4; ++ni)
            oacc[ni] = __builtin_amdgcn_mfma_f32_16x16x32_f16(aq[kd], bs[ni][kd], oacc[ni], 0, 0, 0);
    __syncthreads();   // denf ready

    const int b = bh >> 3, h = bh & 7;
    #pragma unroll
    for (int ni = 0; ni < 4; ++ni) {
        const int e = ni * 16 + r15;
        #pragma unroll
        for (int r = 0; r < 4; ++r) {
            const int qn = qrow + r;
            const float ov = oacc[ni][r] * denf[qn];
            attnh[((size_t)(b * kN + ch * 64 + qn)) * 512 + h * 64 + e] = (_Float16)ov;
        }
    }
}

// ---------------------------------------------------------------------------
extern "C" void kernel_launch(void* const* d_in, const int* in_sizes, int n_in,
                              void* d_out, int out_size, void* d_ws, size_t ws_size,
                              hipStream_t stream)
{
    const float* x  = (const float*)d_in[0];
    const float* Wq = (const float*)d_in[1];
    const float* Wk = (const float*)d_in[2];
    const float* Wv = (const float*)d_in[3];
    const float* Wo = (const float*)d_in[4];
    const float* bo = (const float*)d_in[5];
    float* out = (float*)d_out;

    char* ws = (char*)d_ws;
    _Float16* qh     = (_Float16*)(ws + 0);          // 4,194,304 B [bh][n][64]
    _Float16* khb    = (_Float16*)(ws + 4194304);    // 4,194,304 B [bh][n][64]
    _Float16* kTh    = (_Float16*)(ws + 8388608);    // 4,194,304 B [bh][64][n]
    _Float16* vTh    = (_Float16*)(ws + 12582912);   // 4,194,304 B [bh][64][n]
    float*    cbuf   = (float*)(ws + 16777216);      // 8,519,680 B [bh][ch][4160] f32
    _Float16* spre16 = (_Float16*)(ws + 25296896);   // 4,259,840 B [bh][ch][4160] f16
    float*    zpre   = (float*)(ws + 29556736);      //   131,072 B [bh][ch][64] f32
    _Float16* attnh  = (_Float16*)(ws + 29687808);   // 4,194,304 B [4096][512] f16
    _Float16* WT     = (_Float16*)(ws + 33882112);   // 1,572,864 B [1536][512] f16
    _Float16* WoT    = (_Float16*)(ws + 35454976);   //   524,288 B [512][512] f16
    unsigned* cnt    = (unsigned*)(ws + 35979264);   //        16 B barrier counter

    prep_kernel<<<dim3(16, 16, 4), 256, 0, stream>>>(Wq, Wk, Wv, Wo, WT, WoT, cnt);
    mfma_gemm_kernel<0><<<dim3(12, NROWS / 128), 256, 0, stream>>>(
        x, nullptr, WT, nullptr, nullptr, qh, khb, kTh, vTh);
    mid_kernel<<<dim3(NCH, kBH), 256, 0, stream>>>(
        qh, khb, kTh, vTh, cbuf, spre16, zpre, attnh, cnt);
    mfma_gemm_kernel<1><<<dim3(4, NROWS / 128), 256, 0, stream>>>(
        nullptr, attnh, WoT, bo, out, nullptr, nullptr, nullptr, nullptr);
}

// Round 5
// 72.853 us; speedup vs baseline: 2.4147x; 2.4147x over previous
//
#include <hip/hip_runtime.h>

// Problem constants (reference: B=2, N=2048, DIM=512, H=8, DH=64)
constexpr int kB   = 2;
constexpr int kN   = 2048;
constexpr int kDIM = 512;
constexpr int kH   = 8;
constexpr int kDH  = 64;
constexpr int kBH  = kB * kH;          // 16
constexpr int NROWS = kB * kN;         // 4096
constexpr int CHUNK = 64;
constexpr int NCH   = kN / CHUNK;      // 32
constexpr int CBSTRIDE = kDH * kDH + kDH;  // 4160 per (bh,chunk): ST[e][d] (4096) + z (64)
constexpr float kEPS = 1e-3f;

typedef _Float16 f16x8 __attribute__((ext_vector_type(8)));
typedef _Float16 f16x4 __attribute__((ext_vector_type(4)));
typedef float    floatx4 __attribute__((ext_vector_type(4)));

__device__ __forceinline__ void async_copy16(void* lds, const void* g) {
    __builtin_amdgcn_global_load_lds(
        (const __attribute__((address_space(1))) void*)g,
        (__attribute__((address_space(3))) void*)lds,
        16, 0, 0);
}

// ---------------------------------------------------------------------------
// Prep: transpose+convert weights to fp16 (WT[n][k]).
// z = 0,1,2 -> Wq,Wk,Wv into fused WT[1536][512]; z = 3 -> Wo into WoT.
// ---------------------------------------------------------------------------
__global__ __launch_bounds__(256)
void prep_kernel(const float* __restrict__ Wq, const float* __restrict__ Wk,
                 const float* __restrict__ Wv, const float* __restrict__ Wo,
                 _Float16* __restrict__ WT, _Float16* __restrict__ WoT)
{
    __shared__ float tile[32][33];
    const int z = blockIdx.z;
    const float* src = (z == 0) ? Wq : (z == 1) ? Wk : (z == 2) ? Wv : Wo;
    _Float16* dst = (z < 3) ? (WT + (size_t)z * 512 * 512) : WoT;
    const int r0 = blockIdx.y * 32, c0 = blockIdx.x * 32;
    const int tr = threadIdx.x >> 5, tc = threadIdx.x & 31;
    #pragma unroll
    for (int i = 0; i < 4; ++i)
        tile[tr + 8 * i][tc] = src[(size_t)(r0 + tr + 8 * i) * 512 + c0 + tc];
    __syncthreads();
    #pragma unroll
    for (int i = 0; i < 4; ++i)
        dst[(size_t)(c0 + tr + 8 * i) * 512 + r0 + tc] = (_Float16)tile[tc][tr + 8 * i];
}

// ---------------------------------------------------------------------------
// qkv MFMA GEMM.  BM=BN=128, BK=64, 256 threads (4 waves, 2x2).
// A-side: reads fp32 x directly (reg-staged, cvt->f16, swizzled ds_write_b128).
// B-side: fp16 WT via global_load_lds, XOR-swizzled source+read.
// Epilogue -> fp16 qh,khb row-major [bh][n][64] (relu+eps on q,k),
//             fp16 kTh,vTh transposed [bh][d][n].
// ---------------------------------------------------------------------------
__global__ __launch_bounds__(256)
void qkv_gemm_kernel(const float* __restrict__ Af32,
                     const _Float16* __restrict__ BT,
                     _Float16* __restrict__ qh,
                     _Float16* __restrict__ khb,
                     _Float16* __restrict__ kTh,
                     _Float16* __restrict__ vTh)
{
    constexpr int K = 512;
    __shared__ _Float16 As[128 * 64];   // 16 KB, rows of 128 B, swizzled
    __shared__ _Float16 Bs[128 * 64];   // 16 KB

    const int t = threadIdx.x;
    const int l = t & 63;
    const int w = t >> 6;
    const int wm = w >> 1, wn = w & 1;
    const int m0 = blockIdx.y * 128;
    const int n0 = blockIdx.x * 128;

    const int r15 = l & 15, kq = l >> 4, sw = r15 & 7;

    floatx4 acc[4][4];
    #pragma unroll
    for (int mi = 0; mi < 4; ++mi)
        #pragma unroll
        for (int ni = 0; ni < 4; ++ni)
            acc[mi][ni] = (floatx4){0.f, 0.f, 0.f, 0.f};

    const int srow  = t >> 3;       // 0..31
    const int sslot = t & 7;        // 16B slot within 128B row

    const char* Bbase = (const char*)(BT + (size_t)n0 * K);
    char* AsB = (char*)As;
    char* BsB = (char*)Bs;

    const char* ArdB = (const char*)As + (wm * 64 + r15) * 128;
    const char* BrdB = (const char*)Bs + (wn * 64 + r15) * 128;
    const int sw0 = ((kq ^ sw) << 4);
    const int sw1 = (((4 + kq) ^ sw) << 4);

    for (int k0 = 0; k0 < K; k0 += 64) {
        // B tile: async global->LDS, source pre-inverse-swizzled
        #pragma unroll
        for (int i = 0; i < 4; ++i) {
            const int row = i * 32 + srow;
            const int gsl = sslot ^ (row & 7);
            async_copy16(BsB + row * 128 + sslot * 16,
                         Bbase + (size_t)row * (K * 2) + k0 * 2 + gsl * 16);
        }
        // A tile: reg-staged from fp32, convert, swizzled ds_write
        #pragma unroll
        for (int i = 0; i < 4; ++i) {
            const int s = i * 256 + t;          // 0..1023 16B-slots
            const int row = s >> 3, sl = s & 7;
            const float* xp = Af32 + (size_t)(m0 + row) * K + k0 + sl * 8;
            const float4 a0 = *(const float4*)(xp);
            const float4 a1 = *(const float4*)(xp + 4);
            f16x8 v;
            v[0] = (_Float16)a0.x; v[1] = (_Float16)a0.y;
            v[2] = (_Float16)a0.z; v[3] = (_Float16)a0.w;
            v[4] = (_Float16)a1.x; v[5] = (_Float16)a1.y;
            v[6] = (_Float16)a1.z; v[7] = (_Float16)a1.w;
            *(f16x8*)(AsB + row * 128 + ((sl ^ (row & 7)) << 4)) = v;
        }
        __syncthreads();

        f16x8 af[4][2], bf[4][2];
        #pragma unroll
        for (int i = 0; i < 4; ++i) {
            af[i][0] = *(const f16x8*)(ArdB + i * 2048 + sw0);
            af[i][1] = *(const f16x8*)(ArdB + i * 2048 + sw1);
            bf[i][0] = *(const f16x8*)(BrdB + i * 2048 + sw0);
            bf[i][1] = *(const f16x8*)(BrdB + i * 2048 + sw1);
        }
        #pragma unroll
        for (int kk = 0; kk < 2; ++kk)
            #pragma unroll
            for (int mi = 0; mi < 4; ++mi)
                #pragma unroll
                for (int ni = 0; ni < 4; ++ni)
                    acc[mi][ni] = __builtin_amdgcn_mfma_f32_16x16x32_f16(
                        af[mi][kk], bf[ni][kk], acc[mi][ni], 0, 0, 0);
        __syncthreads();
    }

    // Epilogue.  C fragment: row = kq*4 + r, col = r15 (within each 16x16).
    #pragma unroll
    for (int ni = 0; ni < 4; ++ni) {
        const int col = n0 + wn * 64 + ni * 16 + r15;   // 0..1535
        const int which = col >> 9;
        const int h = (col >> 6) & 7, e = col & 63;
        #pragma unroll
        for (int mi = 0; mi < 4; ++mi) {
            const int row0 = m0 + wm * 64 + mi * 16 + kq * 4;
            const int b = row0 >> 11, nn = row0 & 2047;
            const int bh = b * 8 + h;
            float vv[4];
            #pragma unroll
            for (int r = 0; r < 4; ++r) {
                float v = acc[mi][ni][r];
                if (which < 2) v = fmaxf(v, 0.f) + kEPS;
                vv[r] = v;
            }
            if (which == 0) {
                #pragma unroll
                for (int r = 0; r < 4; ++r)
                    qh[((size_t)bh * kN + nn + r) * 64 + e] = (_Float16)vv[r];
            } else if (which == 1) {
                #pragma unroll
                for (int r = 0; r < 4; ++r)
                    khb[((size_t)bh * kN + nn + r) * 64 + e] = (_Float16)vv[r];
                f16x4 t4;
                t4[0] = (_Float16)vv[0]; t4[1] = (_Float16)vv[1];
                t4[2] = (_Float16)vv[2]; t4[3] = (_Float16)vv[3];
                *(f16x4*)(kTh + ((size_t)bh * 64 + e) * kN + nn) = t4;
            } else {
                f16x4 t4;
                t4[0] = (_Float16)vv[0]; t4[1] = (_Float16)vv[1];
                t4[2] = (_Float16)vv[2]; t4[3] = (_Float16)vv[3];
                *(f16x4*)(vTh + ((size_t)bh * 64 + e) * kN + nn) = t4;
            }
        }
    }
}

// ---------------------------------------------------------------------------
// chunk_sum (MFMA): ST_c[e][d] = sum_n v[n][e] k[n][d]  (A=vT, B=kT, K-dim=n)
// z_c[d] = sum_n k[n][d].  grid (NCH, BH), block 256.
// ---------------------------------------------------------------------------
__global__ __launch_bounds__(256)
void chunk_sum_kernel(const _Float16* __restrict__ kTh, const _Float16* __restrict__ vTh,
                      float* __restrict__ cbuf)
{
    const int ch = blockIdx.x, bh = blockIdx.y;
    const int t = threadIdx.x, l = t & 63, w = t >> 6;
    const int r15 = l & 15, kq = l >> 4;

    const _Float16* vbase = vTh + (size_t)bh * 64 * kN + ch * 64;
    const _Float16* kbase = kTh + (size_t)bh * 64 * kN + ch * 64;

    f16x8 av[2], bk[4][2];
    #pragma unroll
    for (int kk = 0; kk < 2; ++kk) {
        av[kk] = *(const f16x8*)(vbase + (size_t)(w * 16 + r15) * kN + kk * 32 + kq * 8);
        #pragma unroll
        for (int ni = 0; ni < 4; ++ni)
            bk[ni][kk] = *(const f16x8*)(kbase + (size_t)(ni * 16 + r15) * kN + kk * 32 + kq * 8);
    }
    floatx4 acc[4];
    #pragma unroll
    for (int ni = 0; ni < 4; ++ni) acc[ni] = (floatx4){0.f, 0.f, 0.f, 0.f};
    #pragma unroll
    for (int kk = 0; kk < 2; ++kk)
        #pragma unroll
        for (int ni = 0; ni < 4; ++ni)
            acc[ni] = __builtin_amdgcn_mfma_f32_16x16x32_f16(av[kk], bk[ni][kk], acc[ni], 0, 0, 0);

    float* out = cbuf + ((size_t)bh * NCH + ch) * CBSTRIDE;
    #pragma unroll
    for (int ni = 0; ni < 4; ++ni)
        #pragma unroll
        for (int r = 0; r < 4; ++r)
            out[(size_t)(w * 16 + kq * 4 + r) * 64 + ni * 16 + r15] = acc[ni][r];

    if (t < 64) {
        const _Float16* kp = kbase + (size_t)t * kN;
        float z = 0.f;
        #pragma unroll
        for (int j = 0; j < 8; ++j) {
            f16x8 v8 = *(const f16x8*)(kp + j * 8);
            #pragma unroll
            for (int u = 0; u < 8; ++u) z += (float)v8[u];
        }
        out[4096 + t] = z;
    }
}

// ---------------------------------------------------------------------------
// exclusive prefix over chunks; writes fp16 STpre (B-operand layout [e][d])
// and fp32 z_pre.  grid (17, BH), block 256.
// ---------------------------------------------------------------------------
__global__ __launch_bounds__(256)
void prefix_kernel(const float* __restrict__ cbuf, _Float16* __restrict__ spre16,
                   float* __restrict__ zpre)
{
    const int bh = blockIdx.y;
    const int i = blockIdx.x * 256 + threadIdx.x;
    if (i >= CBSTRIDE) return;
    const float* src = cbuf + (size_t)bh * NCH * CBSTRIDE + i;
    _Float16* dst = spre16 + (size_t)bh * NCH * CBSTRIDE + i;
    float* zp = zpre + (size_t)bh * NCH * 64;
    const bool isz = (i >= 4096);
    float vals[NCH];
    #pragma unroll
    for (int c = 0; c < NCH; ++c) vals[c] = src[(size_t)c * CBSTRIDE];
    float a = 0.f;
    #pragma unroll
    for (int c = 0; c < NCH; ++c) {
        dst[(size_t)c * CBSTRIDE] = (_Float16)a;
        if (isz) zp[c * 64 + (i - 4096)] = a;
        a += vals[c];
    }
}

// ---------------------------------------------------------------------------
// Fused chunk-output + out-projection.
// grid (NCH=32, B=2) = 64 blocks x 512 threads; wave w = head w.
// Per block: for each head, scores = QK^T (masked) -> P (swizzled LDS),
// O = P V + Q STpre, den = rowsum(P)+q.z_pre; attn tile [64][512] fp16 in LDS
// (reusing the P buffer); then out = attn @ WoT + bo for these 64 rows.
// ---------------------------------------------------------------------------
__global__ __launch_bounds__(512, 2)
void chunk_epilogue_kernel(const _Float16* __restrict__ qh,
                           const _Float16* __restrict__ khb,
                           const _Float16* __restrict__ vTh,
                           const _Float16* __restrict__ spre16,
                           const float* __restrict__ zpre,
                           const _Float16* __restrict__ WoT,
                           const float* __restrict__ bo,
                           float* __restrict__ outf)
{
    const int ch = blockIdx.x;      // 0..31
    const int b  = blockIdx.y;      // 0..1
    const int t = threadIdx.x;
    const int w = t >> 6;           // wave index = head
    const int l = t & 63;
    const int r15 = l & 15, kq = l >> 4;
    const int h = w;
    const int bh = b * 8 + h;

    // smem: first used as P[8 heads][64 rows][128 B] (swizzled), then as
    // attn[64 rows][1024 B] (swizzled).  64 KB.
    __shared__ char smem[65536];
    __shared__ float denp[8][64];
    __shared__ float denf[8][64];

    const size_t rowbase = (size_t)bh * kN + (size_t)ch * 64;

    // ---- QK^T ----
    f16x8 aq[4][2];
    #pragma unroll
    for (int mi = 0; mi < 4; ++mi)
        #pragma unroll
        for (int kk = 0; kk < 2; ++kk)
            aq[mi][kk] = *(const f16x8*)(qh + (rowbase + mi * 16 + r15) * 64 + kk * 32 + kq * 8);

    floatx4 sacc[4][4];
    #pragma unroll
    for (int mi = 0; mi < 4; ++mi)
        #pragma unroll
        for (int ni = 0; ni < 4; ++ni)
            sacc[mi][ni] = (floatx4){0.f, 0.f, 0.f, 0.f};
    {
        f16x8 bk[4][2];
        #pragma unroll
        for (int ni = 0; ni < 4; ++ni)
            #pragma unroll
            for (int kk = 0; kk < 2; ++kk)
                bk[ni][kk] = *(const f16x8*)(khb + (rowbase + ni * 16 + r15) * 64 + kk * 32 + kq * 8);
        #pragma unroll
        for (int kk = 0; kk < 2; ++kk)
            #pragma unroll
            for (int mi = 0; mi < 4; ++mi)
                #pragma unroll
                for (int ni = 0; ni < 4; ++ni)
                    sacc[mi][ni] = __builtin_amdgcn_mfma_f32_16x16x32_f16(
                        aq[mi][kk], bk[ni][kk], sacc[mi][ni], 0, 0, 0);
    }

    // mask (m <= row), rowsum partials, P -> swizzled LDS fp16
    char* P = smem + h * 8192;
    float psum[4][4];
    #pragma unroll
    for (int mi = 0; mi < 4; ++mi)
        #pragma unroll
        for (int r = 0; r < 4; ++r) psum[mi][r] = 0.f;
    #pragma unroll
    for (int mi = 0; mi < 4; ++mi) {
        #pragma unroll
        for (int ni = 0; ni < 4; ++ni) {
            const int m = ni * 16 + r15;
            #pragma unroll
            for (int r = 0; r < 4; ++r) {
                const int row = mi * 16 + kq * 4 + r;
                const float v = (m <= row) ? sacc[mi][ni][r] : 0.f;
                psum[mi][r] += v;
                const int byte = row * 128 + ((((unsigned)m >> 3) ^ (row & 7)) << 4) + (m & 7) * 2;
                *(_Float16*)(P + byte) = (_Float16)v;
            }
        }
    }
    #pragma unroll
    for (int mi = 0; mi < 4; ++mi) {
        #pragma unroll
        for (int r = 0; r < 4; ++r) {
            float p = psum[mi][r];
            p += __shfl_xor(p, 1, 16);
            p += __shfl_xor(p, 2, 16);
            p += __shfl_xor(p, 4, 16);
            p += __shfl_xor(p, 8, 16);
            if (r15 == 0) denp[h][mi * 16 + kq * 4 + r] = p;
        }
    }

    // den finalize: lane l handles row l of this head (same-wave LDS is in-order)
    {
        const _Float16* qp = qh + (rowbase + l) * 64;
        const float* zp = zpre + ((size_t)bh * NCH + ch) * 64;
        float s = denp[h][l];
        #pragma unroll
        for (int j = 0; j < 8; ++j) {
            f16x8 q8 = *(const f16x8*)(qp + j * 8);
            #pragma unroll
            for (int u = 0; u < 8; ++u) s += (float)q8[u] * zp[j * 8 + u];
        }
        denf[h][l] = 1.0f / s;
    }

    // ---- O = P V + Q STpre ----
    f16x8 ap[4][2], bv[4][2], bs[4][2];
    #pragma unroll
    for (int mi = 0; mi < 4; ++mi)
        #pragma unroll
        for (int km = 0; km < 2; ++km)
            ap[mi][km] = *(const f16x8*)(P + (mi * 16 + r15) * 128 +
                                         (((km * 4 + kq) ^ (r15 & 7)) << 4));
    #pragma unroll
    for (int ni = 0; ni < 4; ++ni)
        #pragma unroll
        for (int km = 0; km < 2; ++km)
            bv[ni][km] = *(const f16x8*)(vTh + ((size_t)bh * 64 + ni * 16 + r15) * kN +
                                         ch * 64 + km * 32 + kq * 8);
    const _Float16* sp = spre16 + ((size_t)bh * NCH + ch) * CBSTRIDE;
    #pragma unroll
    for (int ni = 0; ni < 4; ++ni)
        #pragma unroll
        for (int kd = 0; kd < 2; ++kd)
            bs[ni][kd] = *(const f16x8*)(sp + (size_t)(ni * 16 + r15) * 64 + kd * 32 + kq * 8);

    floatx4 oacc[4][4];
    #pragma unroll
    for (int mi = 0; mi < 4; ++mi)
        #pragma unroll
        for (int ni = 0; ni < 4; ++ni)
            oacc[mi][ni] = (floatx4){0.f, 0.f, 0.f, 0.f};
    #pragma unroll
    for (int km = 0; km < 2; ++km)
        #pragma unroll
        for (int mi = 0; mi < 4; ++mi)
            #pragma unroll
            for (int ni = 0; ni < 4; ++ni)
                oacc[mi][ni] = __builtin_amdgcn_mfma_f32_16x16x32_f16(
                    ap[mi][km], bv[ni][km], oacc[mi][ni], 0, 0, 0);
    #pragma unroll
    for (int kd = 0; kd < 2; ++kd)
        #pragma unroll
        for (int mi = 0; mi < 4; ++mi)
            #pragma unroll
            for (int ni = 0; ni < 4; ++ni)
                oacc[mi][ni] = __builtin_amdgcn_mfma_f32_16x16x32_f16(
                    aq[mi][kd], bs[ni][kd], oacc[mi][ni], 0, 0, 0);

    __syncthreads();   // all P reads done; denf ready -> smem becomes attn tile

    // attn tile write: [row][1024 B], swizzled 16B slots (slot ^ row&7)
    #pragma unroll
    for (int mi = 0; mi < 4; ++mi) {
        #pragma unroll
        for (int ni = 0; ni < 4; ++ni) {
            const int c = h * 64 + ni * 16 + r15;         // 0..511
            const int slot = c >> 3;
            #pragma unroll
            for (int r = 0; r < 4; ++r) {
                const int row = mi * 16 + kq * 4 + r;
                const float ov = oacc[mi][ni][r] * denf[h][row];
                const int byte = row * 1024 + ((slot ^ (row & 7)) << 4) + (c & 7) * 2;
                *(_Float16*)(smem + byte) = (_Float16)ov;
            }
        }
    }
    __syncthreads();   // full attn tile visible to all waves

    // ---- out-proj: wave w -> out cols w*64 .. w*64+63, K = 512 ----
    floatx4 acc2[4][4];
    #pragma unroll
    for (int mi = 0; mi < 4; ++mi)
        #pragma unroll
        for (int ni = 0; ni < 4; ++ni)
            acc2[mi][ni] = (floatx4){0.f, 0.f, 0.f, 0.f};

    for (int kk = 0; kk < 16; ++kk) {
        f16x8 af2[4], bf2[4];
        #pragma unroll
        for (int mi = 0; mi < 4; ++mi) {
            const int row = mi * 16 + r15;
            af2[mi] = *(const f16x8*)(smem + row * 1024 + (((kk * 4 + kq) ^ (row & 7)) << 4));
        }
        #pragma unroll
        for (int ni = 0; ni < 4; ++ni)
            bf2[ni] = *(const f16x8*)(WoT + ((size_t)(w * 64 + ni * 16 + r15)) * 512 +
                                      kk * 32 + kq * 8);
        #pragma unroll
        for (int mi = 0; mi < 4; ++mi)
            #pragma unroll
            for (int ni = 0; ni < 4; ++ni)
                acc2[mi][ni] = __builtin_amdgcn_mfma_f32_16x16x32_f16(
                    af2[mi], bf2[ni], acc2[mi][ni], 0, 0, 0);
    }

    #pragma unroll
    for (int ni = 0; ni < 4; ++ni) {
        const int col = w * 64 + ni * 16 + r15;
        const float bias = bo[col];
        #pragma unroll
        for (int mi = 0; mi < 4; ++mi) {
            #pragma unroll
            for (int r = 0; r < 4; ++r) {
                const int rowg = b * 2048 + ch * 64 + mi * 16 + kq * 4 + r;
                outf[(size_t)rowg * 512 + col] = acc2[mi][ni][r] + bias;
            }
        }
    }
}

// ---------------------------------------------------------------------------
extern "C" void kernel_launch(void* const* d_in, const int* in_sizes, int n_in,
                              void* d_out, int out_size, void* d_ws, size_t ws_size,
                              hipStream_t stream)
{
    const float* x  = (const float*)d_in[0];
    const float* Wq = (const float*)d_in[1];
    const float* Wk = (const float*)d_in[2];
    const float* Wv = (const float*)d_in[3];
    const float* Wo = (const float*)d_in[4];
    const float* bo = (const float*)d_in[5];
    float* out = (float*)d_out;

    char* ws = (char*)d_ws;
    _Float16* qh     = (_Float16*)(ws + 0);          // 4,194,304 B [bh][n][64]
    _Float16* khb    = (_Float16*)(ws + 4194304);    // 4,194,304 B [bh][n][64]
    _Float16* kTh    = (_Float16*)(ws + 8388608);    // 4,194,304 B [bh][64][n]
    _Float16* vTh    = (_Float16*)(ws + 12582912);   // 4,194,304 B [bh][64][n]
    float*    cbuf   = (float*)(ws + 16777216);      // 8,519,680 B [bh][ch][4160] f32
    _Float16* spre16 = (_Float16*)(ws + 25296896);   // 4,259,840 B [bh][ch][4160] f16
    float*    zpre   = (float*)(ws + 29556736);      //   131,072 B [bh][ch][64] f32
    _Float16* WT     = (_Float16*)(ws + 29687808);   // 1,572,864 B [1536][512] f16
    _Float16* WoT    = (_Float16*)(ws + 31260672);   //   524,288 B [512][512] f16

    prep_kernel<<<dim3(16, 16, 4), 256, 0, stream>>>(Wq, Wk, Wv, Wo, WT, WoT);
    qkv_gemm_kernel<<<dim3(12, NROWS / 128), 256, 0, stream>>>(
        x, WT, qh, khb, kTh, vTh);
    chunk_sum_kernel<<<dim3(NCH, kBH), 256, 0, stream>>>(kTh, vTh, cbuf);
    prefix_kernel<<<dim3(17, kBH), 256, 0, stream>>>(cbuf, spre16, zpre);
    chunk_epilogue_kernel<<<dim3(NCH, kB), 512, 0, stream>>>(
        qh, khb, vTh, spre16, zpre, WoT, bo, out);
}

// Round 6
// 60.597 us; speedup vs baseline: 2.9031x; 1.2023x over previous
//
#include <hip/hip_runtime.h>

// Problem constants (reference: B=2, N=2048, DIM=512, H=8, DH=64)
constexpr int kB   = 2;
constexpr int kN   = 2048;
constexpr int kDIM = 512;
constexpr int kH   = 8;
constexpr int kDH  = 64;
constexpr int kBH  = kB * kH;          // 16
constexpr int NROWS = kB * kN;         // 4096
constexpr int CHUNK = 64;
constexpr int NCH   = kN / CHUNK;      // 32
constexpr int CBSTRIDE = kDH * kDH + kDH;  // 4160 per (bh,chunk): ST[e][d] (4096) + z (64)
constexpr float kEPS = 1e-3f;

typedef _Float16 f16x8 __attribute__((ext_vector_type(8)));
typedef _Float16 f16x4 __attribute__((ext_vector_type(4)));
typedef float    floatx4 __attribute__((ext_vector_type(4)));

__device__ __forceinline__ void async_copy16(void* lds, const void* g) {
    __builtin_amdgcn_global_load_lds(
        (const __attribute__((address_space(1))) void*)g,
        (__attribute__((address_space(3))) void*)lds,
        16, 0, 0);
}

// ---------------------------------------------------------------------------
// Prep: transpose+convert weights to fp16 (WT[n][k]).
// z = 0,1,2 -> Wq,Wk,Wv into fused WT[1536][512]; z = 3 -> Wo into WoT.
// ---------------------------------------------------------------------------
__global__ __launch_bounds__(256)
void prep_kernel(const float* __restrict__ Wq, const float* __restrict__ Wk,
                 const float* __restrict__ Wv, const float* __restrict__ Wo,
                 _Float16* __restrict__ WT, _Float16* __restrict__ WoT)
{
    __shared__ float tile[32][33];
    const int z = blockIdx.z;
    const float* src = (z == 0) ? Wq : (z == 1) ? Wk : (z == 2) ? Wv : Wo;
    _Float16* dst = (z < 3) ? (WT + (size_t)z * 512 * 512) : WoT;
    const int r0 = blockIdx.y * 32, c0 = blockIdx.x * 32;
    const int tr = threadIdx.x >> 5, tc = threadIdx.x & 31;
    #pragma unroll
    for (int i = 0; i < 4; ++i)
        tile[tr + 8 * i][tc] = src[(size_t)(r0 + tr + 8 * i) * 512 + c0 + tc];
    __syncthreads();
    #pragma unroll
    for (int i = 0; i < 4; ++i)
        dst[(size_t)(c0 + tr + 8 * i) * 512 + r0 + tc] = (_Float16)tile[tc][tr + 8 * i];
}

// ---------------------------------------------------------------------------
// qkv MFMA GEMM.  BM=BN=128, BK=64, 256 threads (4 waves, 2x2).
// A-side: reads fp32 x directly (reg-staged, cvt->f16, swizzled ds_write_b128).
// B-side: fp16 WT via global_load_lds, XOR-swizzled source+read.
// Epilogue -> fp16 qh,khb row-major [bh][n][64] (relu+eps on q,k),
//             fp16 kTh,vTh transposed [bh][d][n].
// ---------------------------------------------------------------------------
__global__ __launch_bounds__(256)
void qkv_gemm_kernel(const float* __restrict__ Af32,
                     const _Float16* __restrict__ BT,
                     _Float16* __restrict__ qh,
                     _Float16* __restrict__ khb,
                     _Float16* __restrict__ kTh,
                     _Float16* __restrict__ vTh)
{
    constexpr int K = 512;
    __shared__ _Float16 As[128 * 64];   // 16 KB, rows of 128 B, swizzled
    __shared__ _Float16 Bs[128 * 64];   // 16 KB

    const int t = threadIdx.x;
    const int l = t & 63;
    const int w = t >> 6;
    const int wm = w >> 1, wn = w & 1;
    const int m0 = blockIdx.y * 128;
    const int n0 = blockIdx.x * 128;

    const int r15 = l & 15, kq = l >> 4, sw = r15 & 7;

    floatx4 acc[4][4];
    #pragma unroll
    for (int mi = 0; mi < 4; ++mi)
        #pragma unroll
        for (int ni = 0; ni < 4; ++ni)
            acc[mi][ni] = (floatx4){0.f, 0.f, 0.f, 0.f};

    const int srow  = t >> 3;       // 0..31
    const int sslot = t & 7;        // 16B slot within 128B row

    const char* Bbase = (const char*)(BT + (size_t)n0 * K);
    char* AsB = (char*)As;
    char* BsB = (char*)Bs;

    const char* ArdB = (const char*)As + (wm * 64 + r15) * 128;
    const char* BrdB = (const char*)Bs + (wn * 64 + r15) * 128;
    const int sw0 = ((kq ^ sw) << 4);
    const int sw1 = (((4 + kq) ^ sw) << 4);

    for (int k0 = 0; k0 < K; k0 += 64) {
        // B tile: async global->LDS, source pre-inverse-swizzled
        #pragma unroll
        for (int i = 0; i < 4; ++i) {
            const int row = i * 32 + srow;
            const int gsl = sslot ^ (row & 7);
            async_copy16(BsB + row * 128 + sslot * 16,
                         Bbase + (size_t)row * (K * 2) + k0 * 2 + gsl * 16);
        }
        // A tile: reg-staged from fp32, convert, swizzled ds_write
        #pragma unroll
        for (int i = 0; i < 4; ++i) {
            const int s = i * 256 + t;          // 0..1023 16B-slots
            const int row = s >> 3, sl = s & 7;
            const float* xp = Af32 + (size_t)(m0 + row) * K + k0 + sl * 8;
            const float4 a0 = *(const float4*)(xp);
            const float4 a1 = *(const float4*)(xp + 4);
            f16x8 v;
            v[0] = (_Float16)a0.x; v[1] = (_Float16)a0.y;
            v[2] = (_Float16)a0.z; v[3] = (_Float16)a0.w;
            v[4] = (_Float16)a1.x; v[5] = (_Float16)a1.y;
            v[6] = (_Float16)a1.z; v[7] = (_Float16)a1.w;
            *(f16x8*)(AsB + row * 128 + ((sl ^ (row & 7)) << 4)) = v;
        }
        __syncthreads();

        f16x8 af[4][2], bf[4][2];
        #pragma unroll
        for (int i = 0; i < 4; ++i) {
            af[i][0] = *(const f16x8*)(ArdB + i * 2048 + sw0);
            af[i][1] = *(const f16x8*)(ArdB + i * 2048 + sw1);
            bf[i][0] = *(const f16x8*)(BrdB + i * 2048 + sw0);
            bf[i][1] = *(const f16x8*)(BrdB + i * 2048 + sw1);
        }
        #pragma unroll
        for (int kk = 0; kk < 2; ++kk)
            #pragma unroll
            for (int mi = 0; mi < 4; ++mi)
                #pragma unroll
                for (int ni = 0; ni < 4; ++ni)
                    acc[mi][ni] = __builtin_amdgcn_mfma_f32_16x16x32_f16(
                        af[mi][kk], bf[ni][kk], acc[mi][ni], 0, 0, 0);
        __syncthreads();
    }

    // Epilogue.  C fragment: row = kq*4 + r, col = r15 (within each 16x16).
    #pragma unroll
    for (int ni = 0; ni < 4; ++ni) {
        const int col = n0 + wn * 64 + ni * 16 + r15;   // 0..1535
        const int which = col >> 9;
        const int h = (col >> 6) & 7, e = col & 63;
        #pragma unroll
        for (int mi = 0; mi < 4; ++mi) {
            const int row0 = m0 + wm * 64 + mi * 16 + kq * 4;
            const int b = row0 >> 11, nn = row0 & 2047;
            const int bh = b * 8 + h;
            float vv[4];
            #pragma unroll
            for (int r = 0; r < 4; ++r) {
                float v = acc[mi][ni][r];
                if (which < 2) v = fmaxf(v, 0.f) + kEPS;
                vv[r] = v;
            }
            if (which == 0) {
                #pragma unroll
                for (int r = 0; r < 4; ++r)
                    qh[((size_t)bh * kN + nn + r) * 64 + e] = (_Float16)vv[r];
            } else if (which == 1) {
                #pragma unroll
                for (int r = 0; r < 4; ++r)
                    khb[((size_t)bh * kN + nn + r) * 64 + e] = (_Float16)vv[r];
                f16x4 t4;
                t4[0] = (_Float16)vv[0]; t4[1] = (_Float16)vv[1];
                t4[2] = (_Float16)vv[2]; t4[3] = (_Float16)vv[3];
                *(f16x4*)(kTh + ((size_t)bh * 64 + e) * kN + nn) = t4;
            } else {
                f16x4 t4;
                t4[0] = (_Float16)vv[0]; t4[1] = (_Float16)vv[1];
                t4[2] = (_Float16)vv[2]; t4[3] = (_Float16)vv[3];
                *(f16x4*)(vTh + ((size_t)bh * 64 + e) * kN + nn) = t4;
            }
        }
    }
}

// ---------------------------------------------------------------------------
// chunk_sum (MFMA): ST_c[e][d] = sum_n v[n][e] k[n][d]  (A=vT, B=kT, K-dim=n)
// z_c[d] = sum_n k[n][d].  grid (NCH, BH), block 256.
// ---------------------------------------------------------------------------
__global__ __launch_bounds__(256)
void chunk_sum_kernel(const _Float16* __restrict__ kTh, const _Float16* __restrict__ vTh,
                      float* __restrict__ cbuf)
{
    const int ch = blockIdx.x, bh = blockIdx.y;
    const int t = threadIdx.x, l = t & 63, w = t >> 6;
    const int r15 = l & 15, kq = l >> 4;

    const _Float16* vbase = vTh + (size_t)bh * 64 * kN + ch * 64;
    const _Float16* kbase = kTh + (size_t)bh * 64 * kN + ch * 64;

    f16x8 av[2], bk[4][2];
    #pragma unroll
    for (int kk = 0; kk < 2; ++kk) {
        av[kk] = *(const f16x8*)(vbase + (size_t)(w * 16 + r15) * kN + kk * 32 + kq * 8);
        #pragma unroll
        for (int ni = 0; ni < 4; ++ni)
            bk[ni][kk] = *(const f16x8*)(kbase + (size_t)(ni * 16 + r15) * kN + kk * 32 + kq * 8);
    }
    floatx4 acc[4];
    #pragma unroll
    for (int ni = 0; ni < 4; ++ni) acc[ni] = (floatx4){0.f, 0.f, 0.f, 0.f};
    #pragma unroll
    for (int kk = 0; kk < 2; ++kk)
        #pragma unroll
        for (int ni = 0; ni < 4; ++ni)
            acc[ni] = __builtin_amdgcn_mfma_f32_16x16x32_f16(av[kk], bk[ni][kk], acc[ni], 0, 0, 0);

    float* out = cbuf + ((size_t)bh * NCH + ch) * CBSTRIDE;
    #pragma unroll
    for (int ni = 0; ni < 4; ++ni)
        #pragma unroll
        for (int r = 0; r < 4; ++r)
            out[(size_t)(w * 16 + kq * 4 + r) * 64 + ni * 16 + r15] = acc[ni][r];

    if (t < 64) {
        const _Float16* kp = kbase + (size_t)t * kN;
        float z = 0.f;
        #pragma unroll
        for (int j = 0; j < 8; ++j) {
            f16x8 v8 = *(const f16x8*)(kp + j * 8);
            #pragma unroll
            for (int u = 0; u < 8; ++u) z += (float)v8[u];
        }
        out[4096 + t] = z;
    }
}

// ---------------------------------------------------------------------------
// exclusive prefix over chunks; writes fp16 STpre (B-operand layout [e][d])
// and fp32 z_pre.  grid (17, BH), block 256.
// ---------------------------------------------------------------------------
__global__ __launch_bounds__(256)
void prefix_kernel(const float* __restrict__ cbuf, _Float16* __restrict__ spre16,
                   float* __restrict__ zpre)
{
    const int bh = blockIdx.y;
    const int i = blockIdx.x * 256 + threadIdx.x;
    if (i >= CBSTRIDE) return;
    const float* src = cbuf + (size_t)bh * NCH * CBSTRIDE + i;
    _Float16* dst = spre16 + (size_t)bh * NCH * CBSTRIDE + i;
    float* zp = zpre + (size_t)bh * NCH * 64;
    const bool isz = (i >= 4096);
    float vals[NCH];
    #pragma unroll
    for (int c = 0; c < NCH; ++c) vals[c] = src[(size_t)c * CBSTRIDE];
    float a = 0.f;
    #pragma unroll
    for (int c = 0; c < NCH; ++c) {
        dst[(size_t)c * CBSTRIDE] = (_Float16)a;
        if (isz) zp[c * 64 + (i - 4096)] = a;
        a += vals[c];
    }
}

// ---------------------------------------------------------------------------
// chunk_out (MFMA): scores = QK^T (masked) -> P fp16 in swizzled LDS,
// O = P V + Q STpre, den = rowsum(P) + q.z_pre, attn = O/den (fp16).
// grid (NCH, BH), block 256 (wave w = query rows w*16..w*16+15).
// ---------------------------------------------------------------------------
__global__ __launch_bounds__(256)
void chunk_out_kernel(const _Float16* __restrict__ qh, const _Float16* __restrict__ khb,
                      const _Float16* __restrict__ vTh, const _Float16* __restrict__ spre16,
                      const float* __restrict__ zpre, _Float16* __restrict__ attnh)
{
    const int ch = blockIdx.x, bh = blockIdx.y;
    const int t = threadIdx.x, l = t & 63, w = t >> 6;
    const int r15 = l & 15, kq = l >> 4;

    __shared__ _Float16 Plds[64 * 64];   // swizzled rows of 128 B
    __shared__ float denp[64];
    __shared__ float denf[64];

    const size_t rowbase = (size_t)bh * kN + ch * 64;

    // Phase 1: scores = Q K^T   (A rows = w*16 + r15, K-dim = d = 64)
    f16x8 aq[2], bk[4][2];
    #pragma unroll
    for (int kk = 0; kk < 2; ++kk) {
        aq[kk] = *(const f16x8*)(qh + (rowbase + w * 16 + r15) * 64 + kk * 32 + kq * 8);
        #pragma unroll
        for (int ni = 0; ni < 4; ++ni)
            bk[ni][kk] = *(const f16x8*)(khb + (rowbase + ni * 16 + r15) * 64 + kk * 32 + kq * 8);
    }
    floatx4 sacc[4];
    #pragma unroll
    for (int ni = 0; ni < 4; ++ni) sacc[ni] = (floatx4){0.f, 0.f, 0.f, 0.f};
    #pragma unroll
    for (int kk = 0; kk < 2; ++kk)
        #pragma unroll
        for (int ni = 0; ni < 4; ++ni)
            sacc[ni] = __builtin_amdgcn_mfma_f32_16x16x32_f16(aq[kk], bk[ni][kk], sacc[ni], 0, 0, 0);

    // mask (m <= qn), rowsum, P -> swizzled LDS fp16
    const int qrow = w * 16 + kq * 4;
    float psum[4] = {0.f, 0.f, 0.f, 0.f};
    #pragma unroll
    for (int ni = 0; ni < 4; ++ni) {
        const int m = ni * 16 + r15;
        #pragma unroll
        for (int r = 0; r < 4; ++r) {
            const int row = qrow + r;
            const float v = (m <= row) ? sacc[ni][r] : 0.f;
            psum[r] += v;
            const int byte = row * 128 + ((((unsigned)m >> 3) ^ (row & 7)) << 4) + (m & 7) * 2;
            *(_Float16*)((char*)Plds + byte) = (_Float16)v;
        }
    }
    #pragma unroll
    for (int r = 0; r < 4; ++r) {
        float p = psum[r];
        p += __shfl_xor(p, 1, 16);
        p += __shfl_xor(p, 2, 16);
        p += __shfl_xor(p, 4, 16);
        p += __shfl_xor(p, 8, 16);
        if (r15 == 0) denp[qrow + r] = p;
    }
    __syncthreads();

    // den finalize (64 threads)
    if (t < 64) {
        const _Float16* qp = qh + (rowbase + t) * 64;
        const float* zp = zpre + ((size_t)bh * NCH + ch) * 64;
        float s = denp[t];
        #pragma unroll
        for (int j = 0; j < 8; ++j) {
            f16x8 q8 = *(const f16x8*)(qp + j * 8);
            #pragma unroll
            for (int u = 0; u < 8; ++u) s += (float)q8[u] * zp[j * 8 + u];
        }
        denf[t] = 1.0f / s;
    }

    // Phase 2: O = P V + Q STpre
    f16x8 ap[2], bv[4][2], bs[4][2];
    #pragma unroll
    for (int km = 0; km < 2; ++km)
        ap[km] = *(const f16x8*)((char*)Plds + (w * 16 + r15) * 128 +
                                 (((km * 4 + kq) ^ (r15 & 7)) << 4));
    #pragma unroll
    for (int ni = 0; ni < 4; ++ni) {
        #pragma unroll
        for (int km = 0; km < 2; ++km)
            bv[ni][km] = *(const f16x8*)(vTh + ((size_t)bh * 64 + ni * 16 + r15) * kN +
                                         ch * 64 + km * 32 + kq * 8);
    }
    const _Float16* sp = spre16 + ((size_t)bh * NCH + ch) * CBSTRIDE;
    #pragma unroll
    for (int ni = 0; ni < 4; ++ni)
        #pragma unroll
        for (int kd = 0; kd < 2; ++kd)
            bs[ni][kd] = *(const f16x8*)(sp + (size_t)(ni * 16 + r15) * 64 + kd * 32 + kq * 8);

    floatx4 oacc[4];
    #pragma unroll
    for (int ni = 0; ni < 4; ++ni) oacc[ni] = (floatx4){0.f, 0.f, 0.f, 0.f};
    #pragma unroll
    for (int km = 0; km < 2; ++km)
        #pragma unroll
        for (int ni = 0; ni < 4; ++ni)
            oacc[ni] = __builtin_amdgcn_mfma_f32_16x16x32_f16(ap[km], bv[ni][km], oacc[ni], 0, 0, 0);
    #pragma unroll
    for (int kd = 0; kd < 2; ++kd)
        #pragma unroll
        for (int ni = 0; ni < 4; ++ni)
            oacc[ni] = __builtin_amdgcn_mfma_f32_16x16x32_f16(aq[kd], bs[ni][kd], oacc[ni], 0, 0, 0);
    __syncthreads();   // denf ready

    const int b = bh >> 3, h = bh & 7;
    #pragma unroll
    for (int ni = 0; ni < 4; ++ni) {
        const int e = ni * 16 + r15;
        #pragma unroll
        for (int r = 0; r < 4; ++r) {
            const int qn = qrow + r;
            const float ov = oacc[ni][r] * denf[qn];
            attnh[((size_t)(b * kN + ch * 64 + qn)) * 512 + h * 64 + e] = (_Float16)ov;
        }
    }
}

// ---------------------------------------------------------------------------
// out GEMM: out = attnh @ WoT^T + bo.  BM=BN=128, BK=64, 256 threads.
// A (attnh f16) and B (WoT f16) via global_load_lds, XOR-swizzled.
// ---------------------------------------------------------------------------
__global__ __launch_bounds__(256)
void out_gemm_kernel(const _Float16* __restrict__ A,
                     const _Float16* __restrict__ BT,
                     const float* __restrict__ bo,
                     float* __restrict__ outf)
{
    constexpr int K = 512;
    __shared__ _Float16 As[128 * 64];
    __shared__ _Float16 Bs[128 * 64];

    const int t = threadIdx.x;
    const int l = t & 63;
    const int w = t >> 6;
    const int wm = w >> 1, wn = w & 1;
    const int m0 = blockIdx.y * 128;
    const int n0 = blockIdx.x * 128;

    const int r15 = l & 15, kq = l >> 4, sw = r15 & 7;

    floatx4 acc[4][4];
    #pragma unroll
    for (int mi = 0; mi < 4; ++mi)
        #pragma unroll
        for (int ni = 0; ni < 4; ++ni)
            acc[mi][ni] = (floatx4){0.f, 0.f, 0.f, 0.f};

    const int srow  = t >> 3;
    const int sslot = t & 7;

    const char* Abase = (const char*)(A + (size_t)m0 * K);
    const char* Bbase = (const char*)(BT + (size_t)n0 * K);
    char* AsB = (char*)As;
    char* BsB = (char*)Bs;

    const char* ArdB = (const char*)As + (wm * 64 + r15) * 128;
    const char* BrdB = (const char*)Bs + (wn * 64 + r15) * 128;
    const int sw0 = ((kq ^ sw) << 4);
    const int sw1 = (((4 + kq) ^ sw) << 4);

    for (int k0 = 0; k0 < K; k0 += 64) {
        #pragma unroll
        for (int i = 0; i < 4; ++i) {
            const int row = i * 32 + srow;
            const int gsl = sslot ^ (row & 7);
            async_copy16(AsB + row * 128 + sslot * 16,
                         Abase + (size_t)row * (K * 2) + k0 * 2 + gsl * 16);
            async_copy16(BsB + row * 128 + sslot * 16,
                         Bbase + (size_t)row * (K * 2) + k0 * 2 + gsl * 16);
        }
        __syncthreads();

        f16x8 af[4][2], bf[4][2];
        #pragma unroll
        for (int i = 0; i < 4; ++i) {
            af[i][0] = *(const f16x8*)(ArdB + i * 2048 + sw0);
            af[i][1] = *(const f16x8*)(ArdB + i * 2048 + sw1);
            bf[i][0] = *(const f16x8*)(BrdB + i * 2048 + sw0);
            bf[i][1] = *(const f16x8*)(BrdB + i * 2048 + sw1);
        }
        #pragma unroll
        for (int kk = 0; kk < 2; ++kk)
            #pragma unroll
            for (int mi = 0; mi < 4; ++mi)
                #pragma unroll
                for (int ni = 0; ni < 4; ++ni)
                    acc[mi][ni] = __builtin_amdgcn_mfma_f32_16x16x32_f16(
                        af[mi][kk], bf[ni][kk], acc[mi][ni], 0, 0, 0);
        __syncthreads();
    }

    #pragma unroll
    for (int ni = 0; ni < 4; ++ni) {
        const int col = n0 + wn * 64 + ni * 16 + r15;
        const float bias = bo[col];
        #pragma unroll
        for (int mi = 0; mi < 4; ++mi) {
            const int row = m0 + wm * 64 + mi * 16 + kq * 4;
            #pragma unroll
            for (int r = 0; r < 4; ++r)
                outf[(size_t)(row + r) * 512 + col] = acc[mi][ni][r] + bias;
        }
    }
}

// ---------------------------------------------------------------------------
extern "C" void kernel_launch(void* const* d_in, const int* in_sizes, int n_in,
                              void* d_out, int out_size, void* d_ws, size_t ws_size,
                              hipStream_t stream)
{
    const float* x  = (const float*)d_in[0];
    const float* Wq = (const float*)d_in[1];
    const float* Wk = (const float*)d_in[2];
    const float* Wv = (const float*)d_in[3];
    const float* Wo = (const float*)d_in[4];
    const float* bo = (const float*)d_in[5];
    float* out = (float*)d_out;

    char* ws = (char*)d_ws;
    _Float16* qh     = (_Float16*)(ws + 0);          // 4,194,304 B [bh][n][64]
    _Float16* khb    = (_Float16*)(ws + 4194304);    // 4,194,304 B [bh][n][64]
    _Float16* kTh    = (_Float16*)(ws + 8388608);    // 4,194,304 B [bh][64][n]
    _Float16* vTh    = (_Float16*)(ws + 12582912);   // 4,194,304 B [bh][64][n]
    float*    cbuf   = (float*)(ws + 16777216);      // 8,519,680 B [bh][ch][4160] f32
    _Float16* spre16 = (_Float16*)(ws + 25296896);   // 4,259,840 B [bh][ch][4160] f16
    float*    zpre   = (float*)(ws + 29556736);      //   131,072 B [bh][ch][64] f32
    _Float16* WT     = (_Float16*)(ws + 29687808);   // 1,572,864 B [1536][512] f16
    _Float16* WoT    = (_Float16*)(ws + 31260672);   //   524,288 B [512][512] f16
    _Float16* attnh  = (_Float16*)(ws + 31784960);   // 4,194,304 B [4096][512] f16

    prep_kernel<<<dim3(16, 16, 4), 256, 0, stream>>>(Wq, Wk, Wv, Wo, WT, WoT);
    qkv_gemm_kernel<<<dim3(12, NROWS / 128), 256, 0, stream>>>(
        x, WT, qh, khb, kTh, vTh);
    chunk_sum_kernel<<<dim3(NCH, kBH), 256, 0, stream>>>(kTh, vTh, cbuf);
    prefix_kernel<<<dim3(17, kBH), 256, 0, stream>>>(cbuf, spre16, zpre);
    chunk_out_kernel<<<dim3(NCH, kBH), 256, 0, stream>>>(
        qh, khb, vTh, spre16, zpre, attnh);
    out_gemm_kernel<<<dim3(4, NROWS / 128), 256, 0, stream>>>(
        attnh, WoT, bo, out);
}

// Round 7
// 58.069 us; speedup vs baseline: 3.0295x; 1.0435x over previous
//
#include <hip/hip_runtime.h>

// Problem constants (reference: B=2, N=2048, DIM=512, H=8, DH=64)
constexpr int kB   = 2;
constexpr int kN   = 2048;
constexpr int kDIM = 512;
constexpr int kH   = 8;
constexpr int kDH  = 64;
constexpr int kBH  = kB * kH;          // 16
constexpr int NROWS = kB * kN;         // 4096
constexpr int CHUNK = 64;
constexpr int NCH   = kN / CHUNK;      // 32
constexpr int CBSTRIDE = kDH * kDH + kDH;  // 4160 per (bh,chunk): ST[e][d] (4096) + z (64)
constexpr float kEPS = 1e-3f;

typedef _Float16 f16x8 __attribute__((ext_vector_type(8)));
typedef _Float16 f16x4 __attribute__((ext_vector_type(4)));
typedef float    floatx4 __attribute__((ext_vector_type(4)));

__device__ __forceinline__ void async_copy16(void* lds, const void* g) {
    __builtin_amdgcn_global_load_lds(
        (const __attribute__((address_space(1))) void*)g,
        (__attribute__((address_space(3))) void*)lds,
        16, 0, 0);
}

// ---------------------------------------------------------------------------
// Prep: z=0..3 -> weight transpose+convert (Wq,Wk,Wv -> WT[1536][512], Wo -> WoT);
//       z=4..11 -> x fp32 -> fp16 straight convert (strided strips).
// grid (16,16,12), block 256.
// ---------------------------------------------------------------------------
__global__ __launch_bounds__(256)
void prep_kernel(const float* __restrict__ Wq, const float* __restrict__ Wk,
                 const float* __restrict__ Wv, const float* __restrict__ Wo,
                 const float* __restrict__ x,
                 _Float16* __restrict__ WT, _Float16* __restrict__ WoT,
                 _Float16* __restrict__ xh)
{
    const int z = blockIdx.z;
    if (z >= 4) {
        // x convert: 2,097,152 elems over 8 z-slices x 256 blocks x 256 thr x 4 elems
        const size_t base = (((size_t)(z - 4) * 256 + blockIdx.y * 16 + blockIdx.x) * 256 +
                             threadIdx.x) * 4;
        const float4 a = *(const float4*)(x + base);
        f16x4 o;
        o[0] = (_Float16)a.x; o[1] = (_Float16)a.y;
        o[2] = (_Float16)a.z; o[3] = (_Float16)a.w;
        *(f16x4*)(xh + base) = o;
        return;
    }
    __shared__ float tile[32][33];
    const float* src = (z == 0) ? Wq : (z == 1) ? Wk : (z == 2) ? Wv : Wo;
    _Float16* dst = (z < 3) ? (WT + (size_t)z * 512 * 512) : WoT;
    const int r0 = blockIdx.y * 32, c0 = blockIdx.x * 32;
    const int tr = threadIdx.x >> 5, tc = threadIdx.x & 31;
    #pragma unroll
    for (int i = 0; i < 4; ++i)
        tile[tr + 8 * i][tc] = src[(size_t)(r0 + tr + 8 * i) * 512 + c0 + tc];
    __syncthreads();
    #pragma unroll
    for (int i = 0; i < 4; ++i)
        dst[(size_t)(c0 + tr + 8 * i) * 512 + r0 + tc] = (_Float16)tile[tc][tr + 8 * i];
}

// ---------------------------------------------------------------------------
// qkv MFMA GEMM.  BM=128, BN=256, BK=64, 512 threads (8 waves, 2m x 4n).
// A (xh f16) and B (WT f16) via global_load_lds, XOR-swizzled source+read.
// Epilogue -> fp16 qh,khb row-major [bh][n][64] (relu+eps on q,k),
//             fp16 kTh,vTh transposed [bh][d][n].
// grid (6, 32).
// ---------------------------------------------------------------------------
__global__ __launch_bounds__(512)
void qkv_gemm_kernel(const _Float16* __restrict__ A,
                     const _Float16* __restrict__ BT,
                     _Float16* __restrict__ qh,
                     _Float16* __restrict__ khb,
                     _Float16* __restrict__ kTh,
                     _Float16* __restrict__ vTh)
{
    constexpr int K = 512;
    __shared__ _Float16 As[128 * 64];   // 16 KB, rows of 128 B, swizzled
    __shared__ _Float16 Bs[256 * 64];   // 32 KB

    const int t = threadIdx.x;
    const int l = t & 63;
    const int w = t >> 6;               // 0..7
    const int wm = w >> 2, wn = w & 3;  // 2 x 4 wave grid
    const int m0 = blockIdx.y * 128;
    const int n0 = blockIdx.x * 256;

    const int r15 = l & 15, kq = l >> 4, sw = r15 & 7;

    floatx4 acc[4][4];
    #pragma unroll
    for (int mi = 0; mi < 4; ++mi)
        #pragma unroll
        for (int ni = 0; ni < 4; ++ni)
            acc[mi][ni] = (floatx4){0.f, 0.f, 0.f, 0.f};

    const char* Abase = (const char*)(A + (size_t)m0 * K);
    const char* Bbase = (const char*)(BT + (size_t)n0 * K);
    char* AsB = (char*)As;
    char* BsB = (char*)Bs;

    const char* ArdB = (const char*)As + (wm * 64 + r15) * 128;
    const char* BrdB = (const char*)Bs + (wn * 64 + r15) * 128;
    const int sw0 = ((kq ^ sw) << 4);
    const int sw1 = (((4 + kq) ^ sw) << 4);

    for (int k0 = 0; k0 < K; k0 += 64) {
        // A tile: 1024 16B-slots, 2 rounds of 512 threads
        #pragma unroll
        for (int i = 0; i < 2; ++i) {
            const int s = i * 512 + t;
            const int row = s >> 3, sl = s & 7;
            const int gsl = sl ^ (row & 7);
            async_copy16(AsB + row * 128 + sl * 16,
                         Abase + (size_t)row * (K * 2) + k0 * 2 + gsl * 16);
        }
        // B tile: 2048 16B-slots, 4 rounds
        #pragma unroll
        for (int i = 0; i < 4; ++i) {
            const int s = i * 512 + t;
            const int row = s >> 3, sl = s & 7;
            const int gsl = sl ^ (row & 7);
            async_copy16(BsB + row * 128 + sl * 16,
                         Bbase + (size_t)row * (K * 2) + k0 * 2 + gsl * 16);
        }
        __syncthreads();

        f16x8 af[4][2], bf[4][2];
        #pragma unroll
        for (int i = 0; i < 4; ++i) {
            af[i][0] = *(const f16x8*)(ArdB + i * 2048 + sw0);
            af[i][1] = *(const f16x8*)(ArdB + i * 2048 + sw1);
            bf[i][0] = *(const f16x8*)(BrdB + i * 2048 + sw0);
            bf[i][1] = *(const f16x8*)(BrdB + i * 2048 + sw1);
        }
        #pragma unroll
        for (int kk = 0; kk < 2; ++kk)
            #pragma unroll
            for (int mi = 0; mi < 4; ++mi)
                #pragma unroll
                for (int ni = 0; ni < 4; ++ni)
                    acc[mi][ni] = __builtin_amdgcn_mfma_f32_16x16x32_f16(
                        af[mi][kk], bf[ni][kk], acc[mi][ni], 0, 0, 0);
        __syncthreads();
    }

    // Epilogue.  C fragment: row = kq*4 + r, col = r15 (within each 16x16).
    #pragma unroll
    for (int ni = 0; ni < 4; ++ni) {
        const int col = n0 + wn * 64 + ni * 16 + r15;   // 0..1535
        const int which = col >> 9;
        const int h = (col >> 6) & 7, e = col & 63;
        #pragma unroll
        for (int mi = 0; mi < 4; ++mi) {
            const int row0 = m0 + wm * 64 + mi * 16 + kq * 4;
            const int b = row0 >> 11, nn = row0 & 2047;
            const int bh = b * 8 + h;
            float vv[4];
            #pragma unroll
            for (int r = 0; r < 4; ++r) {
                float v = acc[mi][ni][r];
                if (which < 2) v = fmaxf(v, 0.f) + kEPS;
                vv[r] = v;
            }
            if (which == 0) {
                #pragma unroll
                for (int r = 0; r < 4; ++r)
                    qh[((size_t)bh * kN + nn + r) * 64 + e] = (_Float16)vv[r];
            } else if (which == 1) {
                #pragma unroll
                for (int r = 0; r < 4; ++r)
                    khb[((size_t)bh * kN + nn + r) * 64 + e] = (_Float16)vv[r];
                f16x4 t4;
                t4[0] = (_Float16)vv[0]; t4[1] = (_Float16)vv[1];
                t4[2] = (_Float16)vv[2]; t4[3] = (_Float16)vv[3];
                *(f16x4*)(kTh + ((size_t)bh * 64 + e) * kN + nn) = t4;
            } else {
                f16x4 t4;
                t4[0] = (_Float16)vv[0]; t4[1] = (_Float16)vv[1];
                t4[2] = (_Float16)vv[2]; t4[3] = (_Float16)vv[3];
                *(f16x4*)(vTh + ((size_t)bh * 64 + e) * kN + nn) = t4;
            }
        }
    }
}

// ---------------------------------------------------------------------------
// chunk_sum (MFMA): ST_c[e][d] = sum_n v[n][e] k[n][d]  (A=vT, B=kT, K-dim=n)
// z_c[d] = sum_n k[n][d].  grid (NCH, BH), block 256.
// ---------------------------------------------------------------------------
__global__ __launch_bounds__(256)
void chunk_sum_kernel(const _Float16* __restrict__ kTh, const _Float16* __restrict__ vTh,
                      float* __restrict__ cbuf)
{
    const int ch = blockIdx.x, bh = blockIdx.y;
    const int t = threadIdx.x, l = t & 63, w = t >> 6;
    const int r15 = l & 15, kq = l >> 4;

    const _Float16* vbase = vTh + (size_t)bh * 64 * kN + ch * 64;
    const _Float16* kbase = kTh + (size_t)bh * 64 * kN + ch * 64;

    f16x8 av[2], bk[4][2];
    #pragma unroll
    for (int kk = 0; kk < 2; ++kk) {
        av[kk] = *(const f16x8*)(vbase + (size_t)(w * 16 + r15) * kN + kk * 32 + kq * 8);
        #pragma unroll
        for (int ni = 0; ni < 4; ++ni)
            bk[ni][kk] = *(const f16x8*)(kbase + (size_t)(ni * 16 + r15) * kN + kk * 32 + kq * 8);
    }
    floatx4 acc[4];
    #pragma unroll
    for (int ni = 0; ni < 4; ++ni) acc[ni] = (floatx4){0.f, 0.f, 0.f, 0.f};
    #pragma unroll
    for (int kk = 0; kk < 2; ++kk)
        #pragma unroll
        for (int ni = 0; ni < 4; ++ni)
            acc[ni] = __builtin_amdgcn_mfma_f32_16x16x32_f16(av[kk], bk[ni][kk], acc[ni], 0, 0, 0);

    float* out = cbuf + ((size_t)bh * NCH + ch) * CBSTRIDE;
    #pragma unroll
    for (int ni = 0; ni < 4; ++ni)
        #pragma unroll
        for (int r = 0; r < 4; ++r)
            out[(size_t)(w * 16 + kq * 4 + r) * 64 + ni * 16 + r15] = acc[ni][r];

    if (t < 64) {
        const _Float16* kp = kbase + (size_t)t * kN;
        float z = 0.f;
        #pragma unroll
        for (int j = 0; j < 8; ++j) {
            f16x8 v8 = *(const f16x8*)(kp + j * 8);
            #pragma unroll
            for (int u = 0; u < 8; ++u) z += (float)v8[u];
        }
        out[4096 + t] = z;
    }
}

// ---------------------------------------------------------------------------
// exclusive prefix over chunks; writes fp16 STpre (B-operand layout [e][d])
// and fp32 z_pre.  grid (17, BH), block 256.
// ---------------------------------------------------------------------------
__global__ __launch_bounds__(256)
void prefix_kernel(const float* __restrict__ cbuf, _Float16* __restrict__ spre16,
                   float* __restrict__ zpre)
{
    const int bh = blockIdx.y;
    const int i = blockIdx.x * 256 + threadIdx.x;
    if (i >= CBSTRIDE) return;
    const float* src = cbuf + (size_t)bh * NCH * CBSTRIDE + i;
    _Float16* dst = spre16 + (size_t)bh * NCH * CBSTRIDE + i;
    float* zp = zpre + (size_t)bh * NCH * 64;
    const bool isz = (i >= 4096);
    float vals[NCH];
    #pragma unroll
    for (int c = 0; c < NCH; ++c) vals[c] = src[(size_t)c * CBSTRIDE];
    float a = 0.f;
    #pragma unroll
    for (int c = 0; c < NCH; ++c) {
        dst[(size_t)c * CBSTRIDE] = (_Float16)a;
        if (isz) zp[c * 64 + (i - 4096)] = a;
        a += vals[c];
    }
}

// ---------------------------------------------------------------------------
// chunk_out (MFMA): scores = QK^T (masked) -> P fp16 in swizzled LDS,
// O = P V + Q STpre, den = rowsum(P) + q.z_pre, attn = O/den (fp16).
// grid (NCH, BH), block 256 (wave w = query rows w*16..w*16+15).
// ---------------------------------------------------------------------------
__global__ __launch_bounds__(256)
void chunk_out_kernel(const _Float16* __restrict__ qh, const _Float16* __restrict__ khb,
                      const _Float16* __restrict__ vTh, const _Float16* __restrict__ spre16,
                      const float* __restrict__ zpre, _Float16* __restrict__ attnh)
{
    const int ch = blockIdx.x, bh = blockIdx.y;
    const int t = threadIdx.x, l = t & 63, w = t >> 6;
    const int r15 = l & 15, kq = l >> 4;

    __shared__ _Float16 Plds[64 * 64];   // swizzled rows of 128 B
    __shared__ float denp[64];
    __shared__ float denf[64];

    const size_t rowbase = (size_t)bh * kN + ch * 64;

    // Phase 1: scores = Q K^T   (A rows = w*16 + r15, K-dim = d = 64)
    f16x8 aq[2], bk[4][2];
    #pragma unroll
    for (int kk = 0; kk < 2; ++kk) {
        aq[kk] = *(const f16x8*)(qh + (rowbase + w * 16 + r15) * 64 + kk * 32 + kq * 8);
        #pragma unroll
        for (int ni = 0; ni < 4; ++ni)
            bk[ni][kk] = *(const f16x8*)(khb + (rowbase + ni * 16 + r15) * 64 + kk * 32 + kq * 8);
    }
    floatx4 sacc[4];
    #pragma unroll
    for (int ni = 0; ni < 4; ++ni) sacc[ni] = (floatx4){0.f, 0.f, 0.f, 0.f};
    #pragma unroll
    for (int kk = 0; kk < 2; ++kk)
        #pragma unroll
        for (int ni = 0; ni < 4; ++ni)
            sacc[ni] = __builtin_amdgcn_mfma_f32_16x16x32_f16(aq[kk], bk[ni][kk], sacc[ni], 0, 0, 0);

    // mask (m <= qn), rowsum, P -> swizzled LDS fp16
    const int qrow = w * 16 + kq * 4;
    float psum[4] = {0.f, 0.f, 0.f, 0.f};
    #pragma unroll
    for (int ni = 0; ni < 4; ++ni) {
        const int m = ni * 16 + r15;
        #pragma unroll
        for (int r = 0; r < 4; ++r) {
            const int row = qrow + r;
            const float v = (m <= row) ? sacc[ni][r] : 0.f;
            psum[r] += v;
            const int byte = row * 128 + ((((unsigned)m >> 3) ^ (row & 7)) << 4) + (m & 7) * 2;
            *(_Float16*)((char*)Plds + byte) = (_Float16)v;
        }
    }
    #pragma unroll
    for (int r = 0; r < 4; ++r) {
        float p = psum[r];
        p += __shfl_xor(p, 1, 16);
        p += __shfl_xor(p, 2, 16);
        p += __shfl_xor(p, 4, 16);
        p += __shfl_xor(p, 8, 16);
        if (r15 == 0) denp[qrow + r] = p;
    }
    __syncthreads();

    // den finalize (64 threads)
    if (t < 64) {
        const _Float16* qp = qh + (rowbase + t) * 64;
        const float* zp = zpre + ((size_t)bh * NCH + ch) * 64;
        float s = denp[t];
        #pragma unroll
        for (int j = 0; j < 8; ++j) {
            f16x8 q8 = *(const f16x8*)(qp + j * 8);
            #pragma unroll
            for (int u = 0; u < 8; ++u) s += (float)q8[u] * zp[j * 8 + u];
        }
        denf[t] = 1.0f / s;
    }

    // Phase 2: O = P V + Q STpre
    f16x8 ap[2], bv[4][2], bs[4][2];
    #pragma unroll
    for (int km = 0; km < 2; ++km)
        ap[km] = *(const f16x8*)((char*)Plds + (w * 16 + r15) * 128 +
                                 (((km * 4 + kq) ^ (r15 & 7)) << 4));
    #pragma unroll
    for (int ni = 0; ni < 4; ++ni) {
        #pragma unroll
        for (int km = 0; km < 2; ++km)
            bv[ni][km] = *(const f16x8*)(vTh + ((size_t)bh * 64 + ni * 16 + r15) * kN +
                                         ch * 64 + km * 32 + kq * 8);
    }
    const _Float16* sp = spre16 + ((size_t)bh * NCH + ch) * CBSTRIDE;
    #pragma unroll
    for (int ni = 0; ni < 4; ++ni)
        #pragma unroll
        for (int kd = 0; kd < 2; ++kd)
            bs[ni][kd] = *(const f16x8*)(sp + (size_t)(ni * 16 + r15) * 64 + kd * 32 + kq * 8);

    floatx4 oacc[4];
    #pragma unroll
    for (int ni = 0; ni < 4; ++ni) oacc[ni] = (floatx4){0.f, 0.f, 0.f, 0.f};
    #pragma unroll
    for (int km = 0; km < 2; ++km)
        #pragma unroll
        for (int ni = 0; ni < 4; ++ni)
            oacc[ni] = __builtin_amdgcn_mfma_f32_16x16x32_f16(ap[km], bv[ni][km], oacc[ni], 0, 0, 0);
    #pragma unroll
    for (int kd = 0; kd < 2; ++kd)
        #pragma unroll
        for (int ni = 0; ni < 4; ++ni)
            oacc[ni] = __builtin_amdgcn_mfma_f32_16x16x32_f16(aq[kd], bs[ni][kd], oacc[ni], 0, 0, 0);
    __syncthreads();   // denf ready

    const int b = bh >> 3, h = bh & 7;
    #pragma unroll
    for (int ni = 0; ni < 4; ++ni) {
        const int e = ni * 16 + r15;
        #pragma unroll
        for (int r = 0; r < 4; ++r) {
            const int qn = qrow + r;
            const float ov = oacc[ni][r] * denf[qn];
            attnh[((size_t)(b * kN + ch * 64 + qn)) * 512 + h * 64 + e] = (_Float16)ov;
        }
    }
}

// ---------------------------------------------------------------------------
// out GEMM: out = attnh @ WoT^T + bo.  BM=BN=128, BK=64, 256 threads.
// A (attnh f16) and B (WoT f16) via global_load_lds, XOR-swizzled.
// ---------------------------------------------------------------------------
__global__ __launch_bounds__(256)
void out_gemm_kernel(const _Float16* __restrict__ A,
                     const _Float16* __restrict__ BT,
                     const float* __restrict__ bo,
                     float* __restrict__ outf)
{
    constexpr int K = 512;
    __shared__ _Float16 As[128 * 64];
    __shared__ _Float16 Bs[128 * 64];

    const int t = threadIdx.x;
    const int l = t & 63;
    const int w = t >> 6;
    const int wm = w >> 1, wn = w & 1;
    const int m0 = blockIdx.y * 128;
    const int n0 = blockIdx.x * 128;

    const int r15 = l & 15, kq = l >> 4, sw = r15 & 7;

    floatx4 acc[4][4];
    #pragma unroll
    for (int mi = 0; mi < 4; ++mi)
        #pragma unroll
        for (int ni = 0; ni < 4; ++ni)
            acc[mi][ni] = (floatx4){0.f, 0.f, 0.f, 0.f};

    const int srow  = t >> 3;
    const int sslot = t & 7;

    const char* Abase = (const char*)(A + (size_t)m0 * K);
    const char* Bbase = (const char*)(BT + (size_t)n0 * K);
    char* AsB = (char*)As;
    char* BsB = (char*)Bs;

    const char* ArdB = (const char*)As + (wm * 64 + r15) * 128;
    const char* BrdB = (const char*)Bs + (wn * 64 + r15) * 128;
    const int sw0 = ((kq ^ sw) << 4);
    const int sw1 = (((4 + kq) ^ sw) << 4);

    for (int k0 = 0; k0 < K; k0 += 64) {
        #pragma unroll
        for (int i = 0; i < 4; ++i) {
            const int row = i * 32 + srow;
            const int gsl = sslot ^ (row & 7);
            async_copy16(AsB + row * 128 + sslot * 16,
                         Abase + (size_t)row * (K * 2) + k0 * 2 + gsl * 16);
            async_copy16(BsB + row * 128 + sslot * 16,
                         Bbase + (size_t)row * (K * 2) + k0 * 2 + gsl * 16);
        }
        __syncthreads();

        f16x8 af[4][2], bf[4][2];
        #pragma unroll
        for (int i = 0; i < 4; ++i) {
            af[i][0] = *(const f16x8*)(ArdB + i * 2048 + sw0);
            af[i][1] = *(const f16x8*)(ArdB + i * 2048 + sw1);
            bf[i][0] = *(const f16x8*)(BrdB + i * 2048 + sw0);
            bf[i][1] = *(const f16x8*)(BrdB + i * 2048 + sw1);
        }
        #pragma unroll
        for (int kk = 0; kk < 2; ++kk)
            #pragma unroll
            for (int mi = 0; mi < 4; ++mi)
                #pragma unroll
                for (int ni = 0; ni < 4; ++ni)
                    acc[mi][ni] = __builtin_amdgcn_mfma_f32_16x16x32_f16(
                        af[mi][kk], bf[ni][kk], acc[mi][ni], 0, 0, 0);
        __syncthreads();
    }

    #pragma unroll
    for (int ni = 0; ni < 4; ++ni) {
        const int col = n0 + wn * 64 + ni * 16 + r15;
        const float bias = bo[col];
        #pragma unroll
        for (int mi = 0; mi < 4; ++mi) {
            const int row = m0 + wm * 64 + mi * 16 + kq * 4;
            #pragma unroll
            for (int r = 0; r < 4; ++r)
                outf[(size_t)(row + r) * 512 + col] = acc[mi][ni][r] + bias;
        }
    }
}

// ---------------------------------------------------------------------------
extern "C" void kernel_launch(void* const* d_in, const int* in_sizes, int n_in,
                              void* d_out, int out_size, void* d_ws, size_t ws_size,
                              hipStream_t stream)
{
    const float* x  = (const float*)d_in[0];
    const float* Wq = (const float*)d_in[1];
    const float* Wk = (const float*)d_in[2];
    const float* Wv = (const float*)d_in[3];
    const float* Wo = (const float*)d_in[4];
    const float* bo = (const float*)d_in[5];
    float* out = (float*)d_out;

    char* ws = (char*)d_ws;
    _Float16* qh     = (_Float16*)(ws + 0);          // 4,194,304 B [bh][n][64]
    _Float16* khb    = (_Float16*)(ws + 4194304);    // 4,194,304 B [bh][n][64]
    _Float16* kTh    = (_Float16*)(ws + 8388608);    // 4,194,304 B [bh][64][n]
    _Float16* vTh    = (_Float16*)(ws + 12582912);   // 4,194,304 B [bh][64][n]
    float*    cbuf   = (float*)(ws + 16777216);      // 8,519,680 B [bh][ch][4160] f32
    _Float16* spre16 = (_Float16*)(ws + 25296896);   // 4,259,840 B [bh][ch][4160] f16
    float*    zpre   = (float*)(ws + 29556736);      //   131,072 B [bh][ch][64] f32
    _Float16* WT     = (_Float16*)(ws + 29687808);   // 1,572,864 B [1536][512] f16
    _Float16* WoT    = (_Float16*)(ws + 31260672);   //   524,288 B [512][512] f16
    _Float16* attnh  = (_Float16*)(ws + 31784960);   // 4,194,304 B [4096][512] f16
    _Float16* xh     = (_Float16*)(ws + 35979264);   // 4,194,304 B [4096][512] f16

    prep_kernel<<<dim3(16, 16, 12), 256, 0, stream>>>(Wq, Wk, Wv, Wo, x, WT, WoT, xh);
    qkv_gemm_kernel<<<dim3(6, NROWS / 128), 512, 0, stream>>>(
        xh, WT, qh, khb, kTh, vTh);
    chunk_sum_kernel<<<dim3(NCH, kBH), 256, 0, stream>>>(kTh, vTh, cbuf);
    prefix_kernel<<<dim3(17, kBH), 256, 0, stream>>>(cbuf, spre16, zpre);
    chunk_out_kernel<<<dim3(NCH, kBH), 256, 0, stream>>>(
        qh, khb, vTh, spre16, zpre, attnh);
    out_gemm_kernel<<<dim3(4, NROWS / 128), 256, 0, stream>>>(
        attnh, WoT, bo, out);
}